// Round 2
// baseline (509.587 us; speedup 1.0000x reference)
//
#include <hip/hip_runtime.h>
#include <math.h>

#define T_ 1024
#define BS_ 8
#define D_ 512
#define NROWS_ (BS_*2*T_)   // 16384
#define ALPHA_ 0.1f

// compare-exchange keeping (max, lower-index-on-tie) in (va,ia)
#define CE(va,ia,vb,ib) { bool s_ = (vb > va) || ((vb == va) && (ib < ia)); \
    float tv_ = va; int ti_ = ia; \
    va = s_ ? vb : va; ia = s_ ? ib : ia; \
    vb = s_ ? tv_ : vb; ib = s_ ? ti_ : ib; }

// -------------------- Kernel A: Wh = h @ W  (f32, 8x8 per thread) --------------------
// block = 32 rows x 512 cols, 256 threads; grid = 16384/32 = 512
__global__ __launch_bounds__(256) void k_gemm_wh(
    const float* __restrict__ xa, const float* __restrict__ xv,
    const float* __restrict__ W, float* __restrict__ Wh)
{
    __shared__ float As[16][36];    // [k][row]
    __shared__ float Bs[16][516];   // [k][col]

    const int tid     = threadIdx.x;
    const int rowbase = blockIdx.x << 5;
    const int r8      = (tid >> 6) << 3;   // wave-uniform
    const int c0      = (tid & 63) << 2;   // 0..252

    const int q = rowbase >> 10;           // 0..15, constant per block
    const float* src = ((q & 1) ? xv : xa)
                     + (size_t)((q >> 1) * 1024 + (rowbase & 1023)) * D_;

    float acc[8][8];
    #pragma unroll
    for (int ii = 0; ii < 8; ++ii)
        #pragma unroll
        for (int jj = 0; jj < 8; ++jj) acc[ii][jj] = 0.f;

    for (int k0 = 0; k0 < D_; k0 += 16) {
        if (tid < 128) {
            int row = tid >> 2, k4 = (tid & 3) << 2;
            float4 v = *(const float4*)(src + (size_t)row * D_ + k0 + k4);
            As[k4+0][row] = v.x; As[k4+1][row] = v.y;
            As[k4+2][row] = v.z; As[k4+3][row] = v.w;
        }
        #pragma unroll
        for (int it = 0; it < 8; ++it) {
            int f  = tid + (it << 8);
            int k  = f >> 7, n4 = (f & 127) << 2;
            *(float4*)&Bs[k][n4] = *(const float4*)(W + (size_t)(k0 + k) * D_ + n4);
        }
        __syncthreads();
        #pragma unroll
        for (int k = 0; k < 16; ++k) {
            float4 a0 = *(const float4*)&As[k][r8];
            float4 a1 = *(const float4*)&As[k][r8 + 4];
            float4 b0 = *(const float4*)&Bs[k][c0];
            float4 b1 = *(const float4*)&Bs[k][c0 + 256];
            float av[8] = {a0.x,a0.y,a0.z,a0.w,a1.x,a1.y,a1.z,a1.w};
            float bv[8] = {b0.x,b0.y,b0.z,b0.w,b1.x,b1.y,b1.z,b1.w};
            #pragma unroll
            for (int ii = 0; ii < 8; ++ii)
                #pragma unroll
                for (int jj = 0; jj < 8; ++jj)
                    acc[ii][jj] = fmaf(av[ii], bv[jj], acc[ii][jj]);
        }
        __syncthreads();
    }
    #pragma unroll
    for (int ii = 0; ii < 8; ++ii) {
        float* dst = Wh + (size_t)(rowbase + r8 + ii) * D_;
        *(float4*)(dst + c0)       = make_float4(acc[ii][0], acc[ii][1], acc[ii][2], acc[ii][3]);
        *(float4*)(dst + c0 + 256) = make_float4(acc[ii][4], acc[ii][5], acc[ii][6], acc[ii][7]);
    }
}

// -------------------- Kernel B: row stats Wh1, Wh2, sq --------------------
__global__ __launch_bounds__(256) void k_rowstats(
    const float* __restrict__ Wh, const float* __restrict__ a,
    float* __restrict__ Wh1, float* __restrict__ Wh2, float* __restrict__ sq)
{
    __shared__ float sa[2*D_];
    const int tid = threadIdx.x;
    for (int i = tid; i < 2*D_; i += 256) sa[i] = a[i];
    __syncthreads();

    const int lane = tid & 63;
    const int row  = (blockIdx.x << 2) + (tid >> 6);
    const float* wr = Wh + (size_t)row * D_;

    float s1 = 0.f, s2 = 0.f, ss = 0.f;
    #pragma unroll
    for (int w = 0; w < 2; ++w) {
        int c = (lane + (w << 6)) << 2;
        float4 v = *(const float4*)(wr + c);
        s1 = fmaf(v.x, sa[c+0], s1); s1 = fmaf(v.y, sa[c+1], s1);
        s1 = fmaf(v.z, sa[c+2], s1); s1 = fmaf(v.w, sa[c+3], s1);
        s2 = fmaf(v.x, sa[D_+c+0], s2); s2 = fmaf(v.y, sa[D_+c+1], s2);
        s2 = fmaf(v.z, sa[D_+c+2], s2); s2 = fmaf(v.w, sa[D_+c+3], s2);
        ss = fmaf(v.x, v.x, ss); ss = fmaf(v.y, v.y, ss);
        ss = fmaf(v.z, v.z, ss); ss = fmaf(v.w, v.w, ss);
    }
    #pragma unroll
    for (int off = 32; off > 0; off >>= 1) {
        s1 += __shfl_down(s1, off);
        s2 += __shfl_down(s2, off);
        ss += __shfl_down(ss, off);
    }
    if (lane == 0) { Wh1[row] = s1; Wh2[row] = s2; sq[row] = ss; }
}

// -------------------- Kernel C: per-block Gram + top-4 (8x8 per thread) --------------------
// block = 32 rows x 512 cols (x2 col macro-tiles), 256 threads
// grid = 16 p * 32 row-tiles = 512
__global__ __launch_bounds__(256) void k_gram_topk(
    const float* __restrict__ Wh, const float* __restrict__ sq,
    int* __restrict__ topk)
{
    __shared__ float As[16][36];    // [k][row]
    __shared__ float Bs[16][516];   // [k][col]

    const int tid     = threadIdx.x;
    const int p       = blockIdx.x >> 5;
    const int rt      = blockIdx.x & 31;
    const int rowbase = (p << 10) + (rt << 5);
    const int colbase = p << 10;
    const int r8      = (tid >> 6) << 3;   // wave-uniform
    const int c0      = (tid & 63) << 2;

    // running top-4 per row (sorted desc), fully unrolled indexing only
    float tv[8][4]; int ti[8][4];
    #pragma unroll
    for (int ii = 0; ii < 8; ++ii)
        #pragma unroll
        for (int s = 0; s < 4; ++s) { tv[ii][s] = -3.4e38f; ti[ii][s] = 0; }

    for (int ct = 0; ct < 2; ++ct) {
        const int cb = colbase + (ct << 9);   // absolute col base

        float acc[8][8];
        #pragma unroll
        for (int ii = 0; ii < 8; ++ii)
            #pragma unroll
            for (int jj = 0; jj < 8; ++jj) acc[ii][jj] = 0.f;

        for (int k0 = 0; k0 < D_; k0 += 16) {
            if (tid < 128) {
                int row = tid >> 2, k4 = (tid & 3) << 2;
                float4 v = *(const float4*)(Wh + (size_t)(rowbase + row) * D_ + k0 + k4);
                As[k4+0][row] = v.x; As[k4+1][row] = v.y;
                As[k4+2][row] = v.z; As[k4+3][row] = v.w;
            }
            #pragma unroll
            for (int cc = 0; cc < 8; ++cc) {
                int col = (cc << 6) + (tid >> 2), k4 = (tid & 3) << 2;
                float4 v = *(const float4*)(Wh + (size_t)(cb + col) * D_ + k0 + k4);
                Bs[k4+0][col] = v.x; Bs[k4+1][col] = v.y;
                Bs[k4+2][col] = v.z; Bs[k4+3][col] = v.w;
            }
            __syncthreads();
            #pragma unroll
            for (int k = 0; k < 16; ++k) {
                float4 a0 = *(const float4*)&As[k][r8];
                float4 a1 = *(const float4*)&As[k][r8 + 4];
                float4 b0 = *(const float4*)&Bs[k][c0];
                float4 b1 = *(const float4*)&Bs[k][c0 + 256];
                float av[8] = {a0.x,a0.y,a0.z,a0.w,a1.x,a1.y,a1.z,a1.w};
                float bv[8] = {b0.x,b0.y,b0.z,b0.w,b1.x,b1.y,b1.z,b1.w};
                #pragma unroll
                for (int ii = 0; ii < 8; ++ii)
                    #pragma unroll
                    for (int jj = 0; jj < 8; ++jj)
                        acc[ii][jj] = fmaf(av[ii], bv[jj], acc[ii][jj]);
            }
            __syncthreads();
        }

        // score = 2G - sq_j  (ordering identical to reference pd; -sq_i is a row const)
        float4 s0 = *(const float4*)(sq + cb + c0);
        float4 s1 = *(const float4*)(sq + cb + c0 + 256);
        float sj[8] = {s0.x,s0.y,s0.z,s0.w,s1.x,s1.y,s1.z,s1.w};

        #pragma unroll
        for (int ii = 0; ii < 8; ++ii) {
            #pragma unroll
            for (int jj = 0; jj < 8; ++jj) {
                float x = fmaf(2.f, acc[ii][jj], -sj[jj]);
                int  id = (ct << 9) + ((jj < 4) ? (c0 + jj) : (c0 + 252 + jj));
                float v3 = tv[ii][3];
                if (x > v3) {
                    if (x > tv[ii][2]) {
                        tv[ii][3] = tv[ii][2]; ti[ii][3] = ti[ii][2];
                        if (x > tv[ii][1]) {
                            tv[ii][2] = tv[ii][1]; ti[ii][2] = ti[ii][1];
                            if (x > tv[ii][0]) {
                                tv[ii][1] = tv[ii][0]; ti[ii][1] = ti[ii][0];
                                tv[ii][0] = x; ti[ii][0] = id;
                            } else { tv[ii][1] = x; ti[ii][1] = id; }
                        } else { tv[ii][2] = x; ti[ii][2] = id; }
                    } else { tv[ii][3] = x; ti[ii][3] = id; }
                }
            }
        }
    }

    // butterfly merge across the 64 lanes of each wave (each wave owns 8 rows)
    #pragma unroll
    for (int m = 1; m < 64; m <<= 1) {
        #pragma unroll
        for (int ii = 0; ii < 8; ++ii) {
            float b0 = __shfl_xor(tv[ii][0], m), b1 = __shfl_xor(tv[ii][1], m);
            float b2 = __shfl_xor(tv[ii][2], m), b3 = __shfl_xor(tv[ii][3], m);
            int   j0 = __shfl_xor(ti[ii][0], m), j1 = __shfl_xor(ti[ii][1], m);
            int   j2 = __shfl_xor(ti[ii][2], m), j3 = __shfl_xor(ti[ii][3], m);
            float v0 = tv[ii][0], v1 = tv[ii][1], v2 = tv[ii][2], v3 = tv[ii][3];
            int   i0 = ti[ii][0], i1 = ti[ii][1], i2 = ti[ii][2], i3 = ti[ii][3];
            // bitonic half-cleaner on [v0..v3, b3..b0], keep top4 in v
            CE(v0,i0, b3,j3); CE(v1,i1, b2,j2); CE(v2,i2, b1,j1); CE(v3,i3, b0,j0);
            // sort the 4 (bitonic) descending
            CE(v0,i0, v2,i2); CE(v1,i1, v3,i3);
            CE(v0,i0, v1,i1); CE(v2,i2, v3,i3);
            tv[ii][0]=v0; tv[ii][1]=v1; tv[ii][2]=v2; tv[ii][3]=v3;
            ti[ii][0]=i0; ti[ii][1]=i1; ti[ii][2]=i2; ti[ii][3]=i3;
        }
    }

    const int lane = tid & 63;
    #pragma unroll
    for (int ii = 0; ii < 8; ++ii) {
        if (lane == ii) {
            int row = rowbase + r8 + ii;
            *(int4*)(topk + ((size_t)row << 2)) =
                make_int4(ti[ii][0], ti[ii][1], ti[ii][2], ti[ii][3]);
        }
    }
}

// -------------------- Kernel D: sparse softmax + aggregate + elu --------------------
__global__ __launch_bounds__(256) void k_aggregate(
    const float* __restrict__ Wh, const float* __restrict__ Wh1,
    const float* __restrict__ Wh2, const int* __restrict__ topk,
    float* __restrict__ out)
{
    const int tid  = threadIdx.x;
    const int lane = tid & 63;
    const int r    = (blockIdx.x << 2) + (tid >> 6);
    const int p    = r >> 10;
    const int i    = r & 1023;
    const int rb   = p << 10;

    const int  tM = i - 1, tC = i, tP = i + 1;
    const bool vM = (i > 0), vP = (i < T_ - 1);

    const int* tk = topk + ((size_t)r << 2);
    int s0 = tk[0], s1 = tk[1], s2 = tk[2], s3 = tk[3];

    bool u0 = !((vM && s0 == tM) || (s0 == tC) || (vP && s0 == tP));
    bool u1 = !((vM && s1 == tM) || (s1 == tC) || (vP && s1 == tP));
    bool u2 = !((vM && s2 == tM) || (s2 == tC) || (vP && s2 == tP));
    bool u3 = !((vM && s3 == tM) || (s3 == tC) || (vP && s3 == tP));

    int  ci[7] = { vM ? tM : 0, tC, vP ? tP : 0, s0, s1, s2, s3 };
    bool cv[7] = { vM, true, vP, u0, u1, u2, u3 };

    const float e1 = Wh1[r];
    float ev[7];
    float m = -3.4e38f;
    #pragma unroll
    for (int q = 0; q < 7; ++q) {
        float e = e1 + Wh2[rb + ci[q]];
        e = (e > 0.f) ? e : ALPHA_ * e;
        e = cv[q] ? e : -3.4e38f;
        ev[q] = e;
        m = fmaxf(m, e);
    }
    float wsum = 0.f;
    #pragma unroll
    for (int q = 0; q < 7; ++q) {
        float w = cv[q] ? expf(ev[q] - m) : 0.f;
        ev[q] = w;
        wsum += w;
    }
    #pragma unroll
    for (int q = 0; q < 7; ++q) ev[q] /= wsum;

    const int c0 = lane << 2;
    float4 A0 = {0.f,0.f,0.f,0.f}, A1 = {0.f,0.f,0.f,0.f};
    #pragma unroll
    for (int q = 0; q < 7; ++q) {
        if (ev[q] > 0.f) {
            const float wq = ev[q];
            const float* wrow = Wh + (size_t)(rb + ci[q]) * D_;
            float4 v0 = *(const float4*)(wrow + c0);
            float4 v1 = *(const float4*)(wrow + 256 + c0);
            A0.x = fmaf(wq, v0.x, A0.x); A0.y = fmaf(wq, v0.y, A0.y);
            A0.z = fmaf(wq, v0.z, A0.z); A0.w = fmaf(wq, v0.w, A0.w);
            A1.x = fmaf(wq, v1.x, A1.x); A1.y = fmaf(wq, v1.y, A1.y);
            A1.z = fmaf(wq, v1.z, A1.z); A1.w = fmaf(wq, v1.w, A1.w);
        }
    }
    A0.x = (A0.x > 0.f) ? A0.x : expm1f(A0.x);
    A0.y = (A0.y > 0.f) ? A0.y : expm1f(A0.y);
    A0.z = (A0.z > 0.f) ? A0.z : expm1f(A0.z);
    A0.w = (A0.w > 0.f) ? A0.w : expm1f(A0.w);
    A1.x = (A1.x > 0.f) ? A1.x : expm1f(A1.x);
    A1.y = (A1.y > 0.f) ? A1.y : expm1f(A1.y);
    A1.z = (A1.z > 0.f) ? A1.z : expm1f(A1.z);
    A1.w = (A1.w > 0.f) ? A1.w : expm1f(A1.w);

    const int blk = p & 1, b = p >> 1;
    float* dst = out + (size_t)blk * ((size_t)BS_ * T_ * D_)
               + ((size_t)((b << 10) + i)) * D_;
    *(float4*)(dst + c0)       = A0;
    *(float4*)(dst + 256 + c0) = A1;
}

extern "C" void kernel_launch(void* const* d_in, const int* in_sizes, int n_in,
                              void* d_out, int out_size, void* d_ws, size_t ws_size,
                              hipStream_t stream)
{
    const float* xa = (const float*)d_in[0];
    const float* xv = (const float*)d_in[1];
    const float* W  = (const float*)d_in[2];
    const float* a  = (const float*)d_in[3];
    float* out = (float*)d_out;

    float* Wh  = (float*)d_ws;
    float* Wh1 = Wh  + (size_t)NROWS_ * D_;
    float* Wh2 = Wh1 + NROWS_;
    float* sq  = Wh2 + NROWS_;
    int*  topk = (int*)(sq + NROWS_);

    k_gemm_wh  <<<dim3(512),  dim3(256), 0, stream>>>(xa, xv, W, Wh);
    k_rowstats <<<dim3(4096), dim3(256), 0, stream>>>(Wh, a, Wh1, Wh2, sq);
    k_gram_topk<<<dim3(512),  dim3(256), 0, stream>>>(Wh, sq, topk);
    k_aggregate<<<dim3(4096), dim3(256), 0, stream>>>(Wh, Wh1, Wh2, topk, out);
}

// Round 3
// 227.425 us; speedup vs baseline: 2.2407x; 2.2407x over previous
//
#include <hip/hip_runtime.h>
#include <math.h>

#define T_ 1024
#define BS_ 8
#define D_ 512
#define NROWS_ (BS_*2*T_)   // 16384
#define ALPHA_ 0.1f

typedef _Float16 f16;
typedef _Float16 f16x8 __attribute__((ext_vector_type(8)));
typedef _Float16 f16x4 __attribute__((ext_vector_type(4)));
typedef float f32x4 __attribute__((ext_vector_type(4)));

#define MFMA16(A,B,C) __builtin_amdgcn_mfma_f32_16x16x32_f16((A),(B),(C),0,0,0)

__device__ __forceinline__ void gl16(const void* g, void* l) {
    __builtin_amdgcn_global_load_lds(
        (const __attribute__((address_space(1))) unsigned int*)g,
        (__attribute__((address_space(3))) unsigned int*)l, 16, 0, 0);
}

// branchless sorted-desc top-4 insert (ties keep earlier = lower index)
#define INS4(TV, TI, X, ID) { \
    bool g3 = (X) > TV[3], g2 = (X) > TV[2], g1 = (X) > TV[1], g0 = (X) > TV[0]; \
    TV[3] = g2 ? TV[2] : (g3 ? (X) : TV[3]); TI[3] = g2 ? TI[2] : (g3 ? (ID) : TI[3]); \
    TV[2] = g1 ? TV[1] : (g2 ? (X) : TV[2]); TI[2] = g1 ? TI[1] : (g2 ? (ID) : TI[2]); \
    TV[1] = g0 ? TV[0] : (g1 ? (X) : TV[1]); TI[1] = g0 ? TI[0] : (g1 ? (ID) : TI[1]); \
    TV[0] = g0 ? (X) : TV[0]; TI[0] = g0 ? (ID) : TI[0]; }

// compare-exchange keeping (max, lower-index-on-tie) in (va,ia)
#define CE(va,ia,vb,ib) { bool s_ = (vb > va) || ((vb == va) && (ib < ia)); \
    float tv_ = va; int ti_ = ia; \
    va = s_ ? vb : va; ia = s_ ? ib : ia; \
    vb = s_ ? tv_ : vb; ib = s_ ? ti_ : ib; }

// ---------- Kernel A: Wh = h @ W (f32 8x8) + fused rowstats + fp16 hi/lo split ----------
// block = 32 rows x 512 cols, 256 threads; grid = 512
__global__ __launch_bounds__(256) void k_gemm_wh(
    const float* __restrict__ xa, const float* __restrict__ xv,
    const float* __restrict__ W, const float* __restrict__ a,
    f16* __restrict__ Whh, f16* __restrict__ Whl,
    float* __restrict__ Wh1, float* __restrict__ Wh2, float* __restrict__ sq)
{
    __shared__ float As[16][36];    // [k][row]
    __shared__ float Bs[16][516];   // [k][col]
    __shared__ float sa[1024];

    const int tid     = threadIdx.x;
    const int rowbase = blockIdx.x << 5;
    const int r8      = (tid >> 6) << 3;   // wave-uniform
    const int lane    = tid & 63;
    const int c0      = lane << 2;         // 0..252

    sa[tid] = a[tid]; sa[tid+256] = a[tid+256];
    sa[tid+512] = a[tid+512]; sa[tid+768] = a[tid+768];

    const int q = rowbase >> 10;
    const float* src = ((q & 1) ? xv : xa)
                     + (size_t)((q >> 1) * 1024 + (rowbase & 1023)) * D_;

    float acc[8][8];
    #pragma unroll
    for (int ii = 0; ii < 8; ++ii)
        #pragma unroll
        for (int jj = 0; jj < 8; ++jj) acc[ii][jj] = 0.f;

    for (int k0 = 0; k0 < D_; k0 += 16) {
        if (tid < 128) {
            int row = tid >> 2, k4 = (tid & 3) << 2;
            float4 v = *(const float4*)(src + (size_t)row * D_ + k0 + k4);
            As[k4+0][row] = v.x; As[k4+1][row] = v.y;
            As[k4+2][row] = v.z; As[k4+3][row] = v.w;
        }
        #pragma unroll
        for (int it = 0; it < 8; ++it) {
            int f  = tid + (it << 8);
            int k  = f >> 7, n4 = (f & 127) << 2;
            *(float4*)&Bs[k][n4] = *(const float4*)(W + (size_t)(k0 + k) * D_ + n4);
        }
        __syncthreads();
        #pragma unroll
        for (int k = 0; k < 16; ++k) {
            float4 a0 = *(const float4*)&As[k][r8];
            float4 a1 = *(const float4*)&As[k][r8 + 4];
            float4 b0 = *(const float4*)&Bs[k][c0];
            float4 b1 = *(const float4*)&Bs[k][c0 + 256];
            float av[8] = {a0.x,a0.y,a0.z,a0.w,a1.x,a1.y,a1.z,a1.w};
            float bv[8] = {b0.x,b0.y,b0.z,b0.w,b1.x,b1.y,b1.z,b1.w};
            #pragma unroll
            for (int ii = 0; ii < 8; ++ii)
                #pragma unroll
                for (int jj = 0; jj < 8; ++jj)
                    acc[ii][jj] = fmaf(av[ii], bv[jj], acc[ii][jj]);
        }
        __syncthreads();
    }

    // epilogue: per-row stats (exact f32) + fp16 hi/lo split write
    #pragma unroll
    for (int ii = 0; ii < 8; ++ii) {
        float s1 = 0.f, s2 = 0.f, ss = 0.f;
        #pragma unroll
        for (int j = 0; j < 4; ++j) {
            float xA = acc[ii][j], xB = acc[ii][4+j];
            s1 = fmaf(xA, sa[c0+j], s1);      s1 = fmaf(xB, sa[256+c0+j], s1);
            s2 = fmaf(xA, sa[512+c0+j], s2);  s2 = fmaf(xB, sa[768+c0+j], s2);
            ss = fmaf(xA, xA, ss);            ss = fmaf(xB, xB, ss);
        }
        #pragma unroll
        for (int off = 32; off > 0; off >>= 1) {
            s1 += __shfl_xor(s1, off);
            s2 += __shfl_xor(s2, off);
            ss += __shfl_xor(ss, off);
        }
        const int row = rowbase + r8 + ii;
        if (lane == ii) { Wh1[row] = s1; Wh2[row] = s2; sq[row] = ss; }

        f16x4 hhA, hlA, hhB, hlB;
        #pragma unroll
        for (int j = 0; j < 4; ++j) {
            float xA = acc[ii][j];
            f16 hA = (f16)xA; hhA[j] = hA; hlA[j] = (f16)(xA - (float)hA);
            float xB = acc[ii][4+j];
            f16 hB = (f16)xB; hhB[j] = hB; hlB[j] = (f16)(xB - (float)hB);
        }
        *(f16x4*)(Whh + (size_t)row * D_ + c0)       = hhA;
        *(f16x4*)(Whl + (size_t)row * D_ + c0)       = hlA;
        *(f16x4*)(Whh + (size_t)row * D_ + c0 + 256) = hhB;
        *(f16x4*)(Whl + (size_t)row * D_ + c0 + 256) = hlB;
    }
}

// ---------- Kernel C: split-fp16 MFMA Gram + fused top-4 ----------
// block = 32 rows x 256 cols (ct loop x4 covers 1024 cols), 256 threads (4 waves),
// wave tile 32x64 (rr=2, cr=4). grid = 16p * 32 rowtiles = 512.
// LDS: Bh[0,32K) Bl[32K,64K) Ah[64K,68K) Al[68K,72K) MV[72K,74K) MI[74K,76K)
__global__ __launch_bounds__(256, 2) void k_gram_topk(
    const f16* __restrict__ Whh, const f16* __restrict__ Whl,
    const float* __restrict__ sq, int* __restrict__ topk)
{
    __shared__ __align__(16) unsigned char smem[77824];

    const int tid  = threadIdx.x;
    const int w    = tid >> 6;
    const int lane = tid & 63;
    const int p    = blockIdx.x >> 5;
    const int rt   = blockIdx.x & 31;
    const int prow = p << 10;
    const int rowbase = prow + (rt << 5);

    const int r8  = lane >> 3;          // 0..7  (row within stage unit)
    const int k7  = lane & 7;           // 0..7  (koct within stage unit)
    const int sw2 = ((k7 ^ r8) << 4);   // inverse-swizzled source byte offset
    const int l15 = lane & 15;
    const int q0x = (((lane >> 4) ^ (lane & 7)) << 4);  // swizzled read koct bytes (s=0)

    const char* WhhB = (const char*)Whh;
    const char* WhlB = (const char*)Whl;

    // fragment LDS byte offsets (s=0); s=1 = offset ^ 64
    const int aoff0 = 65536 + ((0  + l15) << 7) + q0x;
    const int aoff1 = 65536 + ((16 + l15) << 7) + q0x;
    const int boff0 = (((w << 6) +  0 + l15) << 7) + q0x;
    const int boff1 = (((w << 6) + 16 + l15) << 7) + q0x;
    const int boff2 = (((w << 6) + 32 + l15) << 7) + q0x;
    const int boff3 = (((w << 6) + 48 + l15) << 7) + q0x;

    float tv[8][4]; int ti[8][4];
    #pragma unroll
    for (int r = 0; r < 8; ++r)
        #pragma unroll
        for (int s = 0; s < 4; ++s) { tv[r][s] = -3.4e38f; ti[r][s] = 0; }

    for (int ct = 0; ct < 4; ++ct) {
        const int colbase = prow + (ct << 8);
        f32x4 acc[2][4];
        #pragma unroll
        for (int m = 0; m < 2; ++m)
            #pragma unroll
            for (int c = 0; c < 4; ++c) acc[m][c] = (f32x4){0.f,0.f,0.f,0.f};

        for (int kc = 0; kc < 8; ++kc) {
            // stage B: wave w stages its own 64 cols (8 units); A: 1 unit/wave
            size_t gB = ((size_t)(colbase + (w << 6) + r8) << 10) + (kc << 7) + sw2;
            int ldsB = (w << 13) + (lane << 4);
            #pragma unroll
            for (int j = 0; j < 8; ++j) {
                gl16(WhhB + gB, smem + ldsB);
                gl16(WhlB + gB, smem + 32768 + ldsB);
                gB += (size_t)8 << 10; ldsB += 1024;
            }
            size_t gA = ((size_t)(rowbase + (w << 3) + r8) << 10) + (kc << 7) + sw2;
            const int ldsA = 65536 + (w << 10) + (lane << 4);
            gl16(WhhB + gA, smem + ldsA);
            gl16(WhlB + gA, smem + 4096 + ldsA);
            __syncthreads();

            #pragma unroll
            for (int s = 0; s < 2; ++s) {
                const int sx = s << 6;
                f16x8 ah0 = *(const f16x8*)(smem + (aoff0 ^ sx));
                f16x8 ah1 = *(const f16x8*)(smem + (aoff1 ^ sx));
                f16x8 al0 = *(const f16x8*)(smem + ((aoff0 ^ sx) + 4096));
                f16x8 al1 = *(const f16x8*)(smem + ((aoff1 ^ sx) + 4096));
                f16x8 bh0 = *(const f16x8*)(smem + (boff0 ^ sx));
                f16x8 bh1 = *(const f16x8*)(smem + (boff1 ^ sx));
                f16x8 bh2 = *(const f16x8*)(smem + (boff2 ^ sx));
                f16x8 bh3 = *(const f16x8*)(smem + (boff3 ^ sx));
                f16x8 bl0 = *(const f16x8*)(smem + ((boff0 ^ sx) + 32768));
                f16x8 bl1 = *(const f16x8*)(smem + ((boff1 ^ sx) + 32768));
                f16x8 bl2 = *(const f16x8*)(smem + ((boff2 ^ sx) + 32768));
                f16x8 bl3 = *(const f16x8*)(smem + ((boff3 ^ sx) + 32768));

                acc[0][0] = MFMA16(ah0, bh0, acc[0][0]);
                acc[0][1] = MFMA16(ah0, bh1, acc[0][1]);
                acc[0][2] = MFMA16(ah0, bh2, acc[0][2]);
                acc[0][3] = MFMA16(ah0, bh3, acc[0][3]);
                acc[1][0] = MFMA16(ah1, bh0, acc[1][0]);
                acc[1][1] = MFMA16(ah1, bh1, acc[1][1]);
                acc[1][2] = MFMA16(ah1, bh2, acc[1][2]);
                acc[1][3] = MFMA16(ah1, bh3, acc[1][3]);
                acc[0][0] = MFMA16(al0, bh0, acc[0][0]);
                acc[0][1] = MFMA16(al0, bh1, acc[0][1]);
                acc[0][2] = MFMA16(al0, bh2, acc[0][2]);
                acc[0][3] = MFMA16(al0, bh3, acc[0][3]);
                acc[1][0] = MFMA16(al1, bh0, acc[1][0]);
                acc[1][1] = MFMA16(al1, bh1, acc[1][1]);
                acc[1][2] = MFMA16(al1, bh2, acc[1][2]);
                acc[1][3] = MFMA16(al1, bh3, acc[1][3]);
                acc[0][0] = MFMA16(ah0, bl0, acc[0][0]);
                acc[0][1] = MFMA16(ah0, bl1, acc[0][1]);
                acc[0][2] = MFMA16(ah0, bl2, acc[0][2]);
                acc[0][3] = MFMA16(ah0, bl3, acc[0][3]);
                acc[1][0] = MFMA16(ah1, bl0, acc[1][0]);
                acc[1][1] = MFMA16(ah1, bl1, acc[1][1]);
                acc[1][2] = MFMA16(ah1, bl2, acc[1][2]);
                acc[1][3] = MFMA16(ah1, bl3, acc[1][3]);
            }
            __syncthreads();
        }

        // epilogue: score = 2G - sq_j, insert 32 candidates
        #pragma unroll
        for (int c = 0; c < 4; ++c) {
            const int cid = (ct << 8) + (w << 6) + (c << 4) + l15;
            const float sqc = sq[prow + cid];
            #pragma unroll
            for (int m = 0; m < 2; ++m)
                #pragma unroll
                for (int j = 0; j < 4; ++j) {
                    float x = fmaf(2.f, acc[m][c][j], -sqc);
                    INS4(tv[(m<<2)+j], ti[(m<<2)+j], x, cid);
                }
        }
    }

    // merge across 16 lanes (same rows: lanes sharing l>>4 cover same 8 row-slots)
    #pragma unroll
    for (int m = 1; m < 16; m <<= 1) {
        #pragma unroll
        for (int r = 0; r < 8; ++r) {
            float b0 = __shfl_xor(tv[r][0], m), b1 = __shfl_xor(tv[r][1], m);
            float b2 = __shfl_xor(tv[r][2], m), b3 = __shfl_xor(tv[r][3], m);
            int   j0 = __shfl_xor(ti[r][0], m), j1 = __shfl_xor(ti[r][1], m);
            int   j2 = __shfl_xor(ti[r][2], m), j3 = __shfl_xor(ti[r][3], m);
            CE(tv[r][0],ti[r][0], b3,j3); CE(tv[r][1],ti[r][1], b2,j2);
            CE(tv[r][2],ti[r][2], b1,j1); CE(tv[r][3],ti[r][3], b0,j0);
            CE(tv[r][0],ti[r][0], tv[r][2],ti[r][2]); CE(tv[r][1],ti[r][1], tv[r][3],ti[r][3]);
            CE(tv[r][0],ti[r][0], tv[r][1],ti[r][1]); CE(tv[r][2],ti[r][2], tv[r][3],ti[r][3]);
        }
    }

    // cross-wave merge via LDS
    if (l15 == 0) {
        const int g = lane >> 4;
        #pragma unroll
        for (int r = 0; r < 8; ++r) {
            const int rl = ((r >> 2) << 4) + (g << 2) + (r & 3);
            *(float4*)(smem + 73728 + (((w << 5) + rl) << 4)) =
                make_float4(tv[r][0], tv[r][1], tv[r][2], tv[r][3]);
            *(int4*)(smem + 75776 + (((w << 5) + rl) << 4)) =
                make_int4(ti[r][0], ti[r][1], ti[r][2], ti[r][3]);
        }
    }
    __syncthreads();
    if (tid < 32) {
        const float* mvp = (const float*)(smem + 73728);
        const int*   mip = (const int*)(smem + 75776);
        float v[4]; int id[4];
        #pragma unroll
        for (int s = 0; s < 4; ++s) { v[s] = mvp[(tid << 2) + s]; id[s] = mip[(tid << 2) + s]; }
        #pragma unroll
        for (int wv = 1; wv < 4; ++wv)
            #pragma unroll
            for (int s = 0; s < 4; ++s) {
                float x = mvp[(((wv << 5) + tid) << 2) + s];
                int  xi = mip[(((wv << 5) + tid) << 2) + s];
                INS4(v, id, x, xi);
            }
        *(int4*)(topk + ((size_t)(rowbase + tid) << 2)) = make_int4(id[0], id[1], id[2], id[3]);
    }
}

// ---------- Kernel D: sparse softmax + aggregate + elu ----------
__global__ __launch_bounds__(256) void k_aggregate(
    const f16* __restrict__ Whh, const f16* __restrict__ Whl,
    const float* __restrict__ Wh1, const float* __restrict__ Wh2,
    const int* __restrict__ topk, float* __restrict__ out)
{
    const int tid  = threadIdx.x;
    const int lane = tid & 63;
    const int r    = (blockIdx.x << 2) + (tid >> 6);
    const int p    = r >> 10;
    const int i    = r & 1023;
    const int rb   = p << 10;

    const int  tM = i - 1, tC = i, tP = i + 1;
    const bool vM = (i > 0), vP = (i < T_ - 1);

    const int* tk = topk + ((size_t)r << 2);
    int s0 = tk[0], s1 = tk[1], s2 = tk[2], s3 = tk[3];

    bool u0 = !((vM && s0 == tM) || (s0 == tC) || (vP && s0 == tP));
    bool u1 = !((vM && s1 == tM) || (s1 == tC) || (vP && s1 == tP));
    bool u2 = !((vM && s2 == tM) || (s2 == tC) || (vP && s2 == tP));
    bool u3 = !((vM && s3 == tM) || (s3 == tC) || (vP && s3 == tP));

    int  ci[7] = { vM ? tM : 0, tC, vP ? tP : 0, s0, s1, s2, s3 };
    bool cv[7] = { vM, true, vP, u0, u1, u2, u3 };

    const float e1 = Wh1[r];
    float ev[7];
    float m = -3.4e38f;
    #pragma unroll
    for (int q = 0; q < 7; ++q) {
        float e = e1 + Wh2[rb + ci[q]];
        e = (e > 0.f) ? e : ALPHA_ * e;
        e = cv[q] ? e : -3.4e38f;
        ev[q] = e;
        m = fmaxf(m, e);
    }
    float wsum = 0.f;
    #pragma unroll
    for (int q = 0; q < 7; ++q) {
        float wq = cv[q] ? expf(ev[q] - m) : 0.f;
        ev[q] = wq;
        wsum += wq;
    }
    #pragma unroll
    for (int q = 0; q < 7; ++q) ev[q] /= wsum;

    const int c0 = lane << 3;   // 8 cols per lane
    float A[8] = {0.f,0.f,0.f,0.f,0.f,0.f,0.f,0.f};
    #pragma unroll
    for (int q = 0; q < 7; ++q) {
        if (ev[q] > 0.f) {
            const float wq = ev[q];
            const size_t ro = (size_t)(rb + ci[q]) * D_ + c0;
            f16x8 vh = *(const f16x8*)(Whh + ro);
            f16x8 vl = *(const f16x8*)(Whl + ro);
            #pragma unroll
            for (int e = 0; e < 8; ++e)
                A[e] = fmaf(wq, (float)vh[e] + (float)vl[e], A[e]);
        }
    }
    #pragma unroll
    for (int e = 0; e < 8; ++e)
        A[e] = (A[e] > 0.f) ? A[e] : expm1f(A[e]);

    const int blk = p & 1, b = p >> 1;
    float* dst = out + (size_t)blk * ((size_t)BS_ * T_ * D_)
               + ((size_t)((b << 10) + i)) * D_;
    *(float4*)(dst + c0)     = make_float4(A[0], A[1], A[2], A[3]);
    *(float4*)(dst + c0 + 4) = make_float4(A[4], A[5], A[6], A[7]);
}

extern "C" void kernel_launch(void* const* d_in, const int* in_sizes, int n_in,
                              void* d_out, int out_size, void* d_ws, size_t ws_size,
                              hipStream_t stream)
{
    const float* xa = (const float*)d_in[0];
    const float* xv = (const float*)d_in[1];
    const float* W  = (const float*)d_in[2];
    const float* a  = (const float*)d_in[3];
    float* out = (float*)d_out;

    f16* Whh   = (f16*)d_ws;                       // 16384*512 fp16 = 16 MB
    f16* Whl   = Whh + (size_t)NROWS_ * D_;        // 16 MB
    float* Wh1 = (float*)(Whl + (size_t)NROWS_ * D_);
    float* Wh2 = Wh1 + NROWS_;
    float* sq  = Wh2 + NROWS_;
    int*  topk = (int*)(sq + NROWS_);

    k_gemm_wh  <<<dim3(512),  dim3(256), 0, stream>>>(xa, xv, W, a, Whh, Whl, Wh1, Wh2, sq);
    k_gram_topk<<<dim3(512),  dim3(256), 0, stream>>>(Whh, Whl, sq, topk);
    k_aggregate<<<dim3(4096), dim3(256), 0, stream>>>(Whh, Whl, Wh1, Wh2, topk, out);
}

// Round 4
// 165.577 us; speedup vs baseline: 3.0776x; 1.3735x over previous
//
#include <hip/hip_runtime.h>
#include <math.h>

#define T_ 1024
#define BS_ 8
#define D_ 512
#define NROWS_ (BS_*2*T_)   // 16384
#define ALPHA_ 0.1f

typedef _Float16 f16;
typedef _Float16 f16x8 __attribute__((ext_vector_type(8)));
typedef _Float16 f16x4 __attribute__((ext_vector_type(4)));
typedef float f32x4 __attribute__((ext_vector_type(4)));

#define MFMA16(A,B,C) __builtin_amdgcn_mfma_f32_16x16x32_f16((A),(B),(C),0,0,0)

__device__ __forceinline__ void gl16(const void* g, void* l) {
    __builtin_amdgcn_global_load_lds(
        (const __attribute__((address_space(1))) unsigned int*)g,
        (__attribute__((address_space(3))) unsigned int*)l, 16, 0, 0);
}

// branchless sorted-desc top-4 insert (ties keep earlier = lower index)
#define INS4(TV, TI, X, ID) { \
    bool g3 = (X) > TV[3], g2 = (X) > TV[2], g1 = (X) > TV[1], g0 = (X) > TV[0]; \
    TV[3] = g2 ? TV[2] : (g3 ? (X) : TV[3]); TI[3] = g2 ? TI[2] : (g3 ? (ID) : TI[3]); \
    TV[2] = g1 ? TV[1] : (g2 ? (X) : TV[2]); TI[2] = g1 ? TI[1] : (g2 ? (ID) : TI[2]); \
    TV[1] = g0 ? TV[0] : (g1 ? (X) : TV[1]); TI[1] = g0 ? TI[0] : (g1 ? (ID) : TI[1]); \
    TV[0] = g0 ? (X) : TV[0]; TI[0] = g0 ? (ID) : TI[0]; }

// compare-exchange keeping (max, lower-index-on-tie) in (va,ia)
#define CE(va,ia,vb,ib) { bool s_ = (vb > va) || ((vb == va) && (ib < ia)); \
    float tv_ = va; int ti_ = ia; \
    va = s_ ? vb : va; ia = s_ ? ib : ia; \
    vb = s_ ? tv_ : vb; ib = s_ ? ti_ : ib; }

// ---------- Kernel 0: W (FIN x FOUT, k-major) -> WT[n][k] f16 hi/lo ----------
// grid = 64 blocks (8x8 tiles of 64x64), 256 threads
__global__ __launch_bounds__(256) void k_splitW(
    const float* __restrict__ W, f16* __restrict__ WTh, f16* __restrict__ WTl)
{
    __shared__ float tile[64][65];
    const int tid = threadIdx.x;
    const int tk = (blockIdx.x >> 3) << 6, tn = (blockIdx.x & 7) << 6;
    const int r0 = tid >> 4, c4 = (tid & 15) << 2;

    #pragma unroll
    for (int rr = 0; rr < 4; ++rr) {
        int k = r0 + (rr << 4);
        float4 v = *(const float4*)(W + (size_t)(tk + k) * D_ + tn + c4);
        tile[k][c4+0] = v.x; tile[k][c4+1] = v.y;
        tile[k][c4+2] = v.z; tile[k][c4+3] = v.w;
    }
    __syncthreads();
    #pragma unroll
    for (int rr = 0; rr < 4; ++rr) {
        int n = r0 + (rr << 4);
        f16x4 h, l;
        #pragma unroll
        for (int i = 0; i < 4; ++i) {
            float x = tile[c4 + i][n];      // = W[tk+c4+i][tn+n]
            f16 hh = (f16)x; h[i] = hh; l[i] = (f16)(x - (float)hh);
        }
        *(f16x4*)(WTh + (size_t)(tn + n) * D_ + tk + c4) = h;
        *(f16x4*)(WTl + (size_t)(tn + n) * D_ + tk + c4) = l;
    }
}

// ---------- Kernel A: Wh = h @ W via split-fp16 MFMA + fused rowstats + hi/lo split ----------
// block = 32 rows x 256 cols (ct<2 covers N=512), 256 threads (4 waves), wave tile 32x64
// grid = 16384/32 = 512
// LDS: Bh[0,32K) Bl[32K,64K) Ah[64K,68K) Al[68K,72K) sa[72K,76K) stats[76K,77.5K)
#define SA_OFF 73728
#define ST_OFF 77824
__global__ __launch_bounds__(256) void k_gemm_wh(
    const float* __restrict__ xa, const float* __restrict__ xv,
    const f16* __restrict__ WTh, const f16* __restrict__ WTl,
    const float* __restrict__ a,
    f16* __restrict__ Whh, f16* __restrict__ Whl,
    float* __restrict__ Wh1, float* __restrict__ Wh2, float* __restrict__ sq)
{
    __shared__ __align__(16) unsigned char smem[79360];

    const int tid  = threadIdx.x;
    const int w    = tid >> 6;
    const int lane = tid & 63;
    const int l15  = lane & 15;
    const int g    = lane >> 4;
    const int rowbase = blockIdx.x << 5;

    // B staging (gl16, pre-split WT): same pattern as gram kernel
    const int r8  = lane >> 3;
    const int k7  = lane & 7;
    const int sw2 = ((k7 ^ r8) << 4);
    // A staging (register round-trip w/ on-the-fly split): thread -> (rowA, koct)
    const int rowA = tid >> 3;
    const int k7A  = tid & 7;
    const int aswz = ((k7A ^ (rowA & 7)) << 4);

    const int q0x = (((lane >> 4) ^ (lane & 7)) << 4);
    const int aoff0 = 65536 + ((0  + l15) << 7) + q0x;
    const int aoff1 = 65536 + ((16 + l15) << 7) + q0x;
    const int boff0 = (((w << 6) +  0 + l15) << 7) + q0x;
    const int boff1 = (((w << 6) + 16 + l15) << 7) + q0x;
    const int boff2 = (((w << 6) + 32 + l15) << 7) + q0x;
    const int boff3 = (((w << 6) + 48 + l15) << 7) + q0x;

    // a-vector into LDS
    *(float4*)(smem + SA_OFF + (tid << 4)) = *(const float4*)(a + (tid << 2));

    const int qp = rowbase >> 10;
    const float* srcA = ((qp & 1) ? xv : xa)
                      + (size_t)((qp >> 1) * 1024 + (rowbase & 1023) + rowA) * D_ + (k7A << 3);

    const char* WThB = (const char*)WTh;
    const char* WTlB = (const char*)WTl;

    float st1[8], st2[8], stq[8];
    #pragma unroll
    for (int s = 0; s < 8; ++s) { st1[s] = 0.f; st2[s] = 0.f; stq[s] = 0.f; }

    for (int ct = 0; ct < 2; ++ct) {
        const int colbase = ct << 8;
        f32x4 acc[2][4];
        #pragma unroll
        for (int m = 0; m < 2; ++m)
            #pragma unroll
            for (int c = 0; c < 4; ++c) acc[m][c] = (f32x4){0.f,0.f,0.f,0.f};

        for (int kc = 0; kc < 8; ++kc) {
            // stage B: wave w stages its 64 WT rows (cols of W)
            size_t gB = ((size_t)(colbase + (w << 6) + r8) << 10) + (kc << 7) + sw2;
            int ldsB = (w << 13) + (lane << 4);
            #pragma unroll
            for (int j = 0; j < 8; ++j) {
                gl16(WThB + gB, smem + ldsB);
                gl16(WTlB + gB, smem + 32768 + ldsB);
                gB += (size_t)8 << 10; ldsB += 1024;
            }
            // stage A: load 8 f32 of x, split hi/lo, swizzled ds_write
            {
                float4 v0 = *(const float4*)(srcA + (kc << 6));
                float4 v1 = *(const float4*)(srcA + (kc << 6) + 4);
                float xs[8] = {v0.x,v0.y,v0.z,v0.w,v1.x,v1.y,v1.z,v1.w};
                f16x8 hi, lo;
                #pragma unroll
                for (int e = 0; e < 8; ++e) {
                    f16 h = (f16)xs[e]; hi[e] = h; lo[e] = (f16)(xs[e] - (float)h);
                }
                const int ldsA = 65536 + (rowA << 7) + aswz;
                *(f16x8*)(smem + ldsA)        = hi;
                *(f16x8*)(smem + ldsA + 4096) = lo;
            }
            __syncthreads();

            #pragma unroll
            for (int s = 0; s < 2; ++s) {
                const int sx = s << 6;
                f16x8 ah0 = *(const f16x8*)(smem + (aoff0 ^ sx));
                f16x8 ah1 = *(const f16x8*)(smem + (aoff1 ^ sx));
                f16x8 al0 = *(const f16x8*)(smem + ((aoff0 ^ sx) + 4096));
                f16x8 al1 = *(const f16x8*)(smem + ((aoff1 ^ sx) + 4096));
                f16x8 bh0 = *(const f16x8*)(smem + (boff0 ^ sx));
                f16x8 bh1 = *(const f16x8*)(smem + (boff1 ^ sx));
                f16x8 bh2 = *(const f16x8*)(smem + (boff2 ^ sx));
                f16x8 bh3 = *(const f16x8*)(smem + (boff3 ^ sx));
                f16x8 bl0 = *(const f16x8*)(smem + ((boff0 ^ sx) + 32768));
                f16x8 bl1 = *(const f16x8*)(smem + ((boff1 ^ sx) + 32768));
                f16x8 bl2 = *(const f16x8*)(smem + ((boff2 ^ sx) + 32768));
                f16x8 bl3 = *(const f16x8*)(smem + ((boff3 ^ sx) + 32768));

                acc[0][0] = MFMA16(ah0, bh0, acc[0][0]);
                acc[0][1] = MFMA16(ah0, bh1, acc[0][1]);
                acc[0][2] = MFMA16(ah0, bh2, acc[0][2]);
                acc[0][3] = MFMA16(ah0, bh3, acc[0][3]);
                acc[1][0] = MFMA16(ah1, bh0, acc[1][0]);
                acc[1][1] = MFMA16(ah1, bh1, acc[1][1]);
                acc[1][2] = MFMA16(ah1, bh2, acc[1][2]);
                acc[1][3] = MFMA16(ah1, bh3, acc[1][3]);
                acc[0][0] = MFMA16(al0, bh0, acc[0][0]);
                acc[0][1] = MFMA16(al0, bh1, acc[0][1]);
                acc[0][2] = MFMA16(al0, bh2, acc[0][2]);
                acc[0][3] = MFMA16(al0, bh3, acc[0][3]);
                acc[1][0] = MFMA16(al1, bh0, acc[1][0]);
                acc[1][1] = MFMA16(al1, bh1, acc[1][1]);
                acc[1][2] = MFMA16(al1, bh2, acc[1][2]);
                acc[1][3] = MFMA16(al1, bh3, acc[1][3]);
                acc[0][0] = MFMA16(ah0, bl0, acc[0][0]);
                acc[0][1] = MFMA16(ah0, bl1, acc[0][1]);
                acc[0][2] = MFMA16(ah0, bl2, acc[0][2]);
                acc[0][3] = MFMA16(ah0, bl3, acc[0][3]);
                acc[1][0] = MFMA16(ah1, bl0, acc[1][0]);
                acc[1][1] = MFMA16(ah1, bl1, acc[1][1]);
                acc[1][2] = MFMA16(ah1, bl2, acc[1][2]);
                acc[1][3] = MFMA16(ah1, bl3, acc[1][3]);
            }
            __syncthreads();
        }

        // epilogue: stats + hi/lo split write of Wh
        #pragma unroll
        for (int c = 0; c < 4; ++c) {
            const int col = (ct << 8) + (w << 6) + (c << 4) + l15;
            const float a1 = *(const float*)(smem + SA_OFF + (col << 2));
            const float a2 = *(const float*)(smem + SA_OFF + 2048 + (col << 2));
            #pragma unroll
            for (int m = 0; m < 2; ++m)
                #pragma unroll
                for (int j = 0; j < 4; ++j) {
                    const float v = acc[m][c][j];
                    const int slot = (m << 2) + j;
                    st1[slot] = fmaf(v, a1, st1[slot]);
                    st2[slot] = fmaf(v, a2, st2[slot]);
                    stq[slot] = fmaf(v, v,  stq[slot]);
                    f16 h = (f16)v; f16 l = (f16)(v - (float)h);
                    const size_t off = (size_t)(rowbase + (m << 4) + (g << 2) + j) * D_ + col;
                    Whh[off] = h; Whl[off] = l;
                }
        }
    }

    // reduce stats over the 16 col-lanes of each group
    #pragma unroll
    for (int mask = 1; mask < 16; mask <<= 1)
        #pragma unroll
        for (int s = 0; s < 8; ++s) {
            st1[s] += __shfl_xor(st1[s], mask);
            st2[s] += __shfl_xor(st2[s], mask);
            stq[s] += __shfl_xor(stq[s], mask);
        }
    if (l15 == 0) {
        #pragma unroll
        for (int s = 0; s < 8; ++s) {
            const int rl = ((s >> 2) << 4) + (g << 2) + (s & 3);
            float* sp = (float*)(smem + ST_OFF) + ((w << 5) + rl) * 3;
            sp[0] = st1[s]; sp[1] = st2[s]; sp[2] = stq[s];
        }
    }
    __syncthreads();
    if (tid < 32) {
        float s1 = 0.f, s2 = 0.f, s3 = 0.f;
        #pragma unroll
        for (int wv = 0; wv < 4; ++wv) {
            const float* sp = (const float*)(smem + ST_OFF) + ((wv << 5) + tid) * 3;
            s1 += sp[0]; s2 += sp[1]; s3 += sp[2];
        }
        Wh1[rowbase + tid] = s1; Wh2[rowbase + tid] = s2; sq[rowbase + tid] = s3;
    }
}

// ---------- Kernel C: split-fp16 MFMA Gram + fused top-4 (unchanged) ----------
__global__ __launch_bounds__(256, 2) void k_gram_topk(
    const f16* __restrict__ Whh, const f16* __restrict__ Whl,
    const float* __restrict__ sq, int* __restrict__ topk)
{
    __shared__ __align__(16) unsigned char smem[77824];

    const int tid  = threadIdx.x;
    const int w    = tid >> 6;
    const int lane = tid & 63;
    const int p    = blockIdx.x >> 5;
    const int rt   = blockIdx.x & 31;
    const int prow = p << 10;
    const int rowbase = prow + (rt << 5);

    const int r8  = lane >> 3;
    const int k7  = lane & 7;
    const int sw2 = ((k7 ^ r8) << 4);
    const int l15 = lane & 15;
    const int q0x = (((lane >> 4) ^ (lane & 7)) << 4);

    const char* WhhB = (const char*)Whh;
    const char* WhlB = (const char*)Whl;

    const int aoff0 = 65536 + ((0  + l15) << 7) + q0x;
    const int aoff1 = 65536 + ((16 + l15) << 7) + q0x;
    const int boff0 = (((w << 6) +  0 + l15) << 7) + q0x;
    const int boff1 = (((w << 6) + 16 + l15) << 7) + q0x;
    const int boff2 = (((w << 6) + 32 + l15) << 7) + q0x;
    const int boff3 = (((w << 6) + 48 + l15) << 7) + q0x;

    float tv[8][4]; int ti[8][4];
    #pragma unroll
    for (int r = 0; r < 8; ++r)
        #pragma unroll
        for (int s = 0; s < 4; ++s) { tv[r][s] = -3.4e38f; ti[r][s] = 0; }

    for (int ct = 0; ct < 4; ++ct) {
        const int colbase = prow + (ct << 8);
        f32x4 acc[2][4];
        #pragma unroll
        for (int m = 0; m < 2; ++m)
            #pragma unroll
            for (int c = 0; c < 4; ++c) acc[m][c] = (f32x4){0.f,0.f,0.f,0.f};

        for (int kc = 0; kc < 8; ++kc) {
            size_t gB = ((size_t)(colbase + (w << 6) + r8) << 10) + (kc << 7) + sw2;
            int ldsB = (w << 13) + (lane << 4);
            #pragma unroll
            for (int j = 0; j < 8; ++j) {
                gl16(WhhB + gB, smem + ldsB);
                gl16(WhlB + gB, smem + 32768 + ldsB);
                gB += (size_t)8 << 10; ldsB += 1024;
            }
            size_t gA = ((size_t)(rowbase + (w << 3) + r8) << 10) + (kc << 7) + sw2;
            const int ldsA = 65536 + (w << 10) + (lane << 4);
            gl16(WhhB + gA, smem + ldsA);
            gl16(WhlB + gA, smem + 4096 + ldsA);
            __syncthreads();

            #pragma unroll
            for (int s = 0; s < 2; ++s) {
                const int sx = s << 6;
                f16x8 ah0 = *(const f16x8*)(smem + (aoff0 ^ sx));
                f16x8 ah1 = *(const f16x8*)(smem + (aoff1 ^ sx));
                f16x8 al0 = *(const f16x8*)(smem + ((aoff0 ^ sx) + 4096));
                f16x8 al1 = *(const f16x8*)(smem + ((aoff1 ^ sx) + 4096));
                f16x8 bh0 = *(const f16x8*)(smem + (boff0 ^ sx));
                f16x8 bh1 = *(const f16x8*)(smem + (boff1 ^ sx));
                f16x8 bh2 = *(const f16x8*)(smem + (boff2 ^ sx));
                f16x8 bh3 = *(const f16x8*)(smem + (boff3 ^ sx));
                f16x8 bl0 = *(const f16x8*)(smem + ((boff0 ^ sx) + 32768));
                f16x8 bl1 = *(const f16x8*)(smem + ((boff1 ^ sx) + 32768));
                f16x8 bl2 = *(const f16x8*)(smem + ((boff2 ^ sx) + 32768));
                f16x8 bl3 = *(const f16x8*)(smem + ((boff3 ^ sx) + 32768));

                acc[0][0] = MFMA16(ah0, bh0, acc[0][0]);
                acc[0][1] = MFMA16(ah0, bh1, acc[0][1]);
                acc[0][2] = MFMA16(ah0, bh2, acc[0][2]);
                acc[0][3] = MFMA16(ah0, bh3, acc[0][3]);
                acc[1][0] = MFMA16(ah1, bh0, acc[1][0]);
                acc[1][1] = MFMA16(ah1, bh1, acc[1][1]);
                acc[1][2] = MFMA16(ah1, bh2, acc[1][2]);
                acc[1][3] = MFMA16(ah1, bh3, acc[1][3]);
                acc[0][0] = MFMA16(al0, bh0, acc[0][0]);
                acc[0][1] = MFMA16(al0, bh1, acc[0][1]);
                acc[0][2] = MFMA16(al0, bh2, acc[0][2]);
                acc[0][3] = MFMA16(al0, bh3, acc[0][3]);
                acc[1][0] = MFMA16(al1, bh0, acc[1][0]);
                acc[1][1] = MFMA16(al1, bh1, acc[1][1]);
                acc[1][2] = MFMA16(al1, bh2, acc[1][2]);
                acc[1][3] = MFMA16(al1, bh3, acc[1][3]);
                acc[0][0] = MFMA16(ah0, bl0, acc[0][0]);
                acc[0][1] = MFMA16(ah0, bl1, acc[0][1]);
                acc[0][2] = MFMA16(ah0, bl2, acc[0][2]);
                acc[0][3] = MFMA16(ah0, bl3, acc[0][3]);
                acc[1][0] = MFMA16(ah1, bl0, acc[1][0]);
                acc[1][1] = MFMA16(ah1, bl1, acc[1][1]);
                acc[1][2] = MFMA16(ah1, bl2, acc[1][2]);
                acc[1][3] = MFMA16(ah1, bl3, acc[1][3]);
            }
            __syncthreads();
        }

        #pragma unroll
        for (int c = 0; c < 4; ++c) {
            const int cid = (ct << 8) + (w << 6) + (c << 4) + l15;
            const float sqc = sq[prow + cid];
            #pragma unroll
            for (int m = 0; m < 2; ++m)
                #pragma unroll
                for (int j = 0; j < 4; ++j) {
                    float x = fmaf(2.f, acc[m][c][j], -sqc);
                    INS4(tv[(m<<2)+j], ti[(m<<2)+j], x, cid);
                }
        }
    }

    #pragma unroll
    for (int m = 1; m < 16; m <<= 1) {
        #pragma unroll
        for (int r = 0; r < 8; ++r) {
            float b0 = __shfl_xor(tv[r][0], m), b1 = __shfl_xor(tv[r][1], m);
            float b2 = __shfl_xor(tv[r][2], m), b3 = __shfl_xor(tv[r][3], m);
            int   j0 = __shfl_xor(ti[r][0], m), j1 = __shfl_xor(ti[r][1], m);
            int   j2 = __shfl_xor(ti[r][2], m), j3 = __shfl_xor(ti[r][3], m);
            CE(tv[r][0],ti[r][0], b3,j3); CE(tv[r][1],ti[r][1], b2,j2);
            CE(tv[r][2],ti[r][2], b1,j1); CE(tv[r][3],ti[r][3], b0,j0);
            CE(tv[r][0],ti[r][0], tv[r][2],ti[r][2]); CE(tv[r][1],ti[r][1], tv[r][3],ti[r][3]);
            CE(tv[r][0],ti[r][0], tv[r][1],ti[r][1]); CE(tv[r][2],ti[r][2], tv[r][3],ti[r][3]);
        }
    }

    if (l15 == 0) {
        const int g = lane >> 4;
        #pragma unroll
        for (int r = 0; r < 8; ++r) {
            const int rl = ((r >> 2) << 4) + (g << 2) + (r & 3);
            *(float4*)(smem + 73728 + (((w << 5) + rl) << 4)) =
                make_float4(tv[r][0], tv[r][1], tv[r][2], tv[r][3]);
            *(int4*)(smem + 75776 + (((w << 5) + rl) << 4)) =
                make_int4(ti[r][0], ti[r][1], ti[r][2], ti[r][3]);
        }
    }
    __syncthreads();
    if (tid < 32) {
        const float* mvp = (const float*)(smem + 73728);
        const int*   mip = (const int*)(smem + 75776);
        float v[4]; int id[4];
        #pragma unroll
        for (int s = 0; s < 4; ++s) { v[s] = mvp[(tid << 2) + s]; id[s] = mip[(tid << 2) + s]; }
        #pragma unroll
        for (int wv = 1; wv < 4; ++wv)
            #pragma unroll
            for (int s = 0; s < 4; ++s) {
                float x = mvp[(((wv << 5) + tid) << 2) + s];
                int  xi = mip[(((wv << 5) + tid) << 2) + s];
                INS4(v, id, x, xi);
            }
        *(int4*)(topk + ((size_t)(rowbase + tid) << 2)) = make_int4(id[0], id[1], id[2], id[3]);
    }
}

// ---------- Kernel D: sparse softmax + aggregate + elu (unchanged) ----------
__global__ __launch_bounds__(256) void k_aggregate(
    const f16* __restrict__ Whh, const f16* __restrict__ Whl,
    const float* __restrict__ Wh1, const float* __restrict__ Wh2,
    const int* __restrict__ topk, float* __restrict__ out)
{
    const int tid  = threadIdx.x;
    const int lane = tid & 63;
    const int r    = (blockIdx.x << 2) + (tid >> 6);
    const int p    = r >> 10;
    const int i    = r & 1023;
    const int rb   = p << 10;

    const int  tM = i - 1, tC = i, tP = i + 1;
    const bool vM = (i > 0), vP = (i < T_ - 1);

    const int* tk = topk + ((size_t)r << 2);
    int s0 = tk[0], s1 = tk[1], s2 = tk[2], s3 = tk[3];

    bool u0 = !((vM && s0 == tM) || (s0 == tC) || (vP && s0 == tP));
    bool u1 = !((vM && s1 == tM) || (s1 == tC) || (vP && s1 == tP));
    bool u2 = !((vM && s2 == tM) || (s2 == tC) || (vP && s2 == tP));
    bool u3 = !((vM && s3 == tM) || (s3 == tC) || (vP && s3 == tP));

    int  ci[7] = { vM ? tM : 0, tC, vP ? tP : 0, s0, s1, s2, s3 };
    bool cv[7] = { vM, true, vP, u0, u1, u2, u3 };

    const float e1 = Wh1[r];
    float ev[7];
    float m = -3.4e38f;
    #pragma unroll
    for (int q = 0; q < 7; ++q) {
        float e = e1 + Wh2[rb + ci[q]];
        e = (e > 0.f) ? e : ALPHA_ * e;
        e = cv[q] ? e : -3.4e38f;
        ev[q] = e;
        m = fmaxf(m, e);
    }
    float wsum = 0.f;
    #pragma unroll
    for (int q = 0; q < 7; ++q) {
        float wq = cv[q] ? expf(ev[q] - m) : 0.f;
        ev[q] = wq;
        wsum += wq;
    }
    #pragma unroll
    for (int q = 0; q < 7; ++q) ev[q] /= wsum;

    const int c0 = lane << 3;
    float A[8] = {0.f,0.f,0.f,0.f,0.f,0.f,0.f,0.f};
    #pragma unroll
    for (int q = 0; q < 7; ++q) {
        if (ev[q] > 0.f) {
            const float wq = ev[q];
            const size_t ro = (size_t)(rb + ci[q]) * D_ + c0;
            f16x8 vh = *(const f16x8*)(Whh + ro);
            f16x8 vl = *(const f16x8*)(Whl + ro);
            #pragma unroll
            for (int e = 0; e < 8; ++e)
                A[e] = fmaf(wq, (float)vh[e] + (float)vl[e], A[e]);
        }
    }
    #pragma unroll
    for (int e = 0; e < 8; ++e)
        A[e] = (A[e] > 0.f) ? A[e] : expm1f(A[e]);

    const int blk = p & 1, b = p >> 1;
    float* dst = out + (size_t)blk * ((size_t)BS_ * T_ * D_)
               + ((size_t)((b << 10) + i)) * D_;
    *(float4*)(dst + c0)     = make_float4(A[0], A[1], A[2], A[3]);
    *(float4*)(dst + c0 + 4) = make_float4(A[4], A[5], A[6], A[7]);
}

extern "C" void kernel_launch(void* const* d_in, const int* in_sizes, int n_in,
                              void* d_out, int out_size, void* d_ws, size_t ws_size,
                              hipStream_t stream)
{
    const float* xa = (const float*)d_in[0];
    const float* xv = (const float*)d_in[1];
    const float* W  = (const float*)d_in[2];
    const float* a  = (const float*)d_in[3];
    float* out = (float*)d_out;

    f16* Whh   = (f16*)d_ws;                       // 16 MB
    f16* Whl   = Whh + (size_t)NROWS_ * D_;        // 16 MB
    f16* WTh   = Whl + (size_t)NROWS_ * D_;        // 0.5 MB
    f16* WTl   = WTh + (size_t)D_ * D_;            // 0.5 MB
    float* Wh1 = (float*)(WTl + (size_t)D_ * D_);
    float* Wh2 = Wh1 + NROWS_;
    float* sq  = Wh2 + NROWS_;
    int*  topk = (int*)(sq + NROWS_);

    k_splitW   <<<dim3(64),   dim3(256), 0, stream>>>(W, WTh, WTl);
    k_gemm_wh  <<<dim3(512),  dim3(256), 0, stream>>>(xa, xv, WTh, WTl, a, Whh, Whl, Wh1, Wh2, sq);
    k_gram_topk<<<dim3(512),  dim3(256), 0, stream>>>(Whh, Whl, sq, topk);
    k_aggregate<<<dim3(4096), dim3(256), 0, stream>>>(Whh, Whl, Wh1, Wh2, topk, out);
}